// Round 1
// baseline (1120.533 us; speedup 1.0000x reference)
//
#include <hip/hip_runtime.h>

#define S (1024*1024)

// A = 0.5*(G - G^T), 1024x1024
__global__ __launch_bounds__(256) void skew_k(const float* __restrict__ G, float* __restrict__ A) {
    int idx = blockIdx.x*blockDim.x + threadIdx.x;
    int r = idx >> 10, c = idx & 1023;
    A[idx] = 0.5f*(G[idx] - G[(c<<10) + r]);
}

// M = (1/6)I + (1/24)A + (1/120)A2 + (1/720)A3
__global__ __launch_bounds__(256) void ewM_k(const float* __restrict__ A, const float* __restrict__ A2,
                                             const float* __restrict__ A3, float* __restrict__ Mo) {
    int idx = blockIdx.x*blockDim.x + threadIdx.x;
    int r = idx >> 10, c = idx & 1023;
    float v = (1.0f/24.0f)*A[idx] + (1.0f/120.0f)*A2[idx] + (1.0f/720.0f)*A3[idx];
    if (r == c) v += (1.0f/6.0f);
    Mo[idx] = v;
}

// E = I + A + 0.5*A2 + T
__global__ __launch_bounds__(256) void ewE_k(const float* __restrict__ A, const float* __restrict__ A2,
                                             const float* __restrict__ T, float* __restrict__ E) {
    int idx = blockIdx.x*blockDim.x + threadIdx.x;
    int r = idx >> 10, c = idx & 1023;
    float v = A[idx] + 0.5f*A2[idx] + T[idx];
    if (r == c) v += 1.0f;
    E[idx] = v;
}

// C = A*B, all 1024x1024 row-major. 64x64 tile, BK=16, 4x4 per thread, 256 threads.
__global__ __launch_bounds__(256) void sgemm64(const float* __restrict__ A, const float* __restrict__ B,
                                               float* __restrict__ C) {
    __shared__ float As[16][65];   // transposed A tile, +1 pad
    __shared__ float Bs[16][64];
    const int tid = threadIdx.x;
    const int tx = tid & 15, ty = tid >> 4;
    const int brow = blockIdx.y << 6, bcol = blockIdx.x << 6;
    const int arow = tid >> 2, acol4 = (tid & 3) << 2;
    const int brw  = tid >> 4, bcol4 = (tid & 15) << 2;
    const float* Ap = A + (brow + arow)*1024 + acol4;
    const float* Bp = B + brw*1024 + bcol + bcol4;
    float acc[4][4] = {};
    for (int k0 = 0; k0 < 1024; k0 += 16) {
        float4 av = *(const float4*)(Ap + k0);
        float4 bv = *(const float4*)(Bp + (k0 << 10));
        As[acol4+0][arow] = av.x;
        As[acol4+1][arow] = av.y;
        As[acol4+2][arow] = av.z;
        As[acol4+3][arow] = av.w;
        *(float4*)&Bs[brw][bcol4] = bv;
        __syncthreads();
        #pragma unroll
        for (int kk = 0; kk < 16; ++kk) {
            float a[4], b[4];
            #pragma unroll
            for (int r = 0; r < 4; ++r) a[r] = As[kk][(ty<<2)+r];
            #pragma unroll
            for (int c = 0; c < 4; ++c) b[c] = Bs[kk][(tx<<2)+c];
            #pragma unroll
            for (int r = 0; r < 4; ++r)
                #pragma unroll
                for (int c = 0; c < 4; ++c)
                    acc[r][c] = fmaf(a[r], b[c], acc[r][c]);
        }
        __syncthreads();
    }
    #pragma unroll
    for (int r = 0; r < 4; ++r) {
        float4 v = make_float4(acc[r][0], acc[r][1], acc[r][2], acc[r][3]);
        *(float4*)&C[(brow + (ty<<2) + r)*1024 + bcol + (tx<<2)] = v;
    }
}

// Y[16384,1024] = X[16384,1024] * R[1024,1024]. 128x128 tile, BK=8, 8x8 per thread.
__global__ __launch_bounds__(256) void sgemm_big(const float* __restrict__ X, const float* __restrict__ R,
                                                 float* __restrict__ Y) {
    __shared__ float As[8][132];   // transposed X tile, +4 pad keeps 16B alignment
    __shared__ float Bs[8][128];
    const int tid = threadIdx.x;
    const int tx = tid & 15, ty = tid >> 4;
    const int brow = blockIdx.y << 7, bcol = blockIdx.x << 7;
    const int arow = tid >> 1, acol4 = (tid & 1) << 2;
    const int brw  = tid >> 5, bcol4 = (tid & 31) << 2;
    const float* Ap = X + (brow + arow)*1024 + acol4;
    const float* Bp = R + brw*1024 + bcol + bcol4;
    float acc[8][8] = {};
    for (int k0 = 0; k0 < 1024; k0 += 8) {
        float4 av = *(const float4*)(Ap + k0);
        float4 bv = *(const float4*)(Bp + (k0 << 10));
        As[acol4+0][arow] = av.x;
        As[acol4+1][arow] = av.y;
        As[acol4+2][arow] = av.z;
        As[acol4+3][arow] = av.w;
        *(float4*)&Bs[brw][bcol4] = bv;
        __syncthreads();
        #pragma unroll
        for (int kk = 0; kk < 8; ++kk) {
            float a[8], b[8];
            *(float4*)(a)   = *(const float4*)&As[kk][(ty<<3)];
            *(float4*)(a+4) = *(const float4*)&As[kk][(ty<<3)+4];
            *(float4*)(b)   = *(const float4*)&Bs[kk][(tx<<3)];
            *(float4*)(b+4) = *(const float4*)&Bs[kk][(tx<<3)+4];
            #pragma unroll
            for (int r = 0; r < 8; ++r)
                #pragma unroll
                for (int c = 0; c < 8; ++c)
                    acc[r][c] = fmaf(a[r], b[c], acc[r][c]);
        }
        __syncthreads();
    }
    #pragma unroll
    for (int r = 0; r < 8; ++r) {
        *(float4*)&Y[(brow+(ty<<3)+r)*1024 + bcol + (tx<<3)]     = *(float4*)&acc[r][0];
        *(float4*)&Y[(brow+(ty<<3)+r)*1024 + bcol + (tx<<3) + 4] = *(float4*)&acc[r][4];
    }
}

extern "C" void kernel_launch(void* const* d_in, const int* in_sizes, int n_in,
                              void* d_out, int out_size, void* d_ws, size_t ws_size,
                              hipStream_t stream) {
    const float* X = (const float*)d_in[0];   // [4,4096,1024] fp32 -> 16384x1024
    const float* G = (const float*)d_in[1];   // [3,1024,1024] fp32
    float* out = (float*)d_out;               // 16384x1024 fp32 (= 16 slots of 1024^2)

    // scratch arena inside d_out (overwritten fully by the final GEMM)
    float* A   = out + 0*S;
    float* A2  = out + 1*S;
    float* A3  = out + 2*S;
    float* Mb  = out + 3*S;
    float* T   = out + 4*S;
    float* E0  = out + 5*S;
    float* E1  = out + 6*S;
    float* E2  = out + 7*S;
    float* R01 = out + 8*S;
    float* R   = (float*)d_ws;                // 4 MB in workspace

    dim3 blk(256);
    dim3 gEW(4096);
    dim3 g64(16, 16);
    dim3 gBig(8, 128);

    for (int i = 0; i < 3; ++i) {
        float* Ei = (i == 0) ? E0 : (i == 1) ? E1 : E2;
        skew_k<<<gEW, blk, 0, stream>>>(G + (size_t)i*S, A);
        sgemm64<<<g64, blk, 0, stream>>>(A,  A,  A2);   // A^2
        sgemm64<<<g64, blk, 0, stream>>>(A2, A,  A3);   // A^3
        ewM_k<<<gEW, blk, 0, stream>>>(A, A2, A3, Mb);  // c3 I + c4 A + c5 A2 + c6 A3
        sgemm64<<<g64, blk, 0, stream>>>(Mb, A3, T);    // degrees 3..6
        ewE_k<<<gEW, blk, 0, stream>>>(A, A2, T, Ei);   // E_i = p6(A_i)
    }
    sgemm64<<<g64, blk, 0, stream>>>(E0,  E1, R01);     // R0*R1
    sgemm64<<<g64, blk, 0, stream>>>(R01, E2, R);       // R = R0*R1*R2  (in d_ws)
    sgemm_big<<<gBig, blk, 0, stream>>>(X, R, out);     // Y = X*R
}

// Round 2
// 329.772 us; speedup vs baseline: 3.3979x; 3.3979x over previous
//
#include <hip/hip_runtime.h>

#define S 1048576
typedef unsigned short u16;
typedef unsigned int u32;
typedef __attribute__((ext_vector_type(8))) short s8v;   // 8 bf16 (4 VGPRs)
typedef __attribute__((ext_vector_type(4))) float f4v;   // MFMA acc

__device__ __forceinline__ float bf2f(u16 u){
    union { float f; u32 u; } v; v.u = ((u32)u) << 16; return v.f;
}
__device__ __forceinline__ u16 f2bf(float x){
    u32 u = __float_as_uint(x);
    u32 r = (u + 0x7FFFu + ((u >> 16) & 1u)) >> 16;   // RNE
    return (u16)r;
}
__device__ __forceinline__ void splitf(float x, u16& h, u16& l){
    h = f2bf(x);
    l = f2bf(x - bf2f(h));
}

// A_z = 0.5*(G_z - G_z^T); writes bf16 split pair (Ah, Al). 64x64 tiles, z=3.
__global__ __launch_bounds__(256) void skew_split_k(const float* __restrict__ G, u16* __restrict__ Abase){
    __shared__ float Gt[64][65];
    const int z = blockIdx.z;
    const float* Gz = G + (size_t)z*S;
    u16* Ah = Abase + (size_t)z*2*S;
    u16* Al = Ah + S;
    const int t = threadIdx.x;
    const int row = t >> 2, cq = (t & 3) << 4;
    const int r0 = blockIdx.y << 6, c0 = blockIdx.x << 6;
    // Gt[r][c] = G[c0+r][r0+c]  (transpose-source tile, coalesced)
    #pragma unroll
    for (int g = 0; g < 4; ++g){
        float4 v = *(const float4*)(Gz + (size_t)(c0+row)*1024 + r0 + cq + g*4);
        Gt[row][cq+g*4+0]=v.x; Gt[row][cq+g*4+1]=v.y; Gt[row][cq+g*4+2]=v.z; Gt[row][cq+g*4+3]=v.w;
    }
    __syncthreads();
    #pragma unroll
    for (int g = 0; g < 2; ++g){
        const float* p = Gz + (size_t)(r0+row)*1024 + c0 + cq + g*8;
        float4 v0 = *(const float4*)(p);
        float4 v1 = *(const float4*)(p+4);
        float xs[8] = {v0.x,v0.y,v0.z,v0.w,v1.x,v1.y,v1.z,v1.w};
        s8v sh, sl;
        #pragma unroll
        for (int i = 0; i < 8; ++i){
            float gt = Gt[cq + g*8 + i][row];       // G[c][r]
            u16 h,l; splitf(0.5f*(xs[i]-gt), h, l);
            sh[i] = (short)h; sl[i] = (short)l;
        }
        *(s8v*)(Ah + (size_t)(r0+row)*1024 + c0 + cq + g*8) = sh;
        *(s8v*)(Al + (size_t)(r0+row)*1024 + c0 + cq + g*8) = sl;
    }
}

// C = A * B with split-bf16 MFMA. A staged from row-major pair (Ah,Al);
// B staged from row-major pair holding B^T (optionally negated: skew trick).
// 64x64 tile, BK=32, 4 waves (each 32x32 = 2x2 frags), z-batched.
__global__ __launch_bounds__(256) void gemm64_k(const u16* __restrict__ Abase, const u16* __restrict__ Btbase,
                                                u16* __restrict__ Cbase, int negb){
    __shared__ u16 Ash[64][40], Asl[64][40], Bsh[64][40], Bsl[64][40];
    const int z = blockIdx.z;
    const u16* Ah = Abase  + (size_t)z*2*S; const u16* Al = Ah + S;
    const u16* Bh = Btbase + (size_t)z*2*S; const u16* Bl = Bh + S;
    u16* Ch = Cbase + (size_t)z*2*S;        u16* Cl = Ch + S;
    const int t = threadIdx.x;
    const int brow = blockIdx.y << 6, bcol = blockIdx.x << 6;
    const int srow = t >> 2, skq = (t & 3) << 3;
    const int lane = t & 63, w = t >> 6;
    const int wm = (w >> 1) << 5, wn = (w & 1) << 5;
    const int lr = lane & 15, lk = (lane >> 4) << 3;
    const short nm = negb ? (short)0x8000 : (short)0;
    const s8v msk = {nm,nm,nm,nm,nm,nm,nm,nm};
    f4v acc[2][2] = {};
    for (int k0 = 0; k0 < 1024; k0 += 32){
        const size_t ao = (size_t)(brow+srow)*1024 + k0 + skq;
        const size_t bo = (size_t)(bcol+srow)*1024 + k0 + skq;
        s8v vah = *(const s8v*)(Ah + ao);
        s8v val = *(const s8v*)(Al + ao);
        s8v vbh = *(const s8v*)(Bh + bo) ^ msk;
        s8v vbl = *(const s8v*)(Bl + bo) ^ msk;
        __syncthreads();
        *(s8v*)&Ash[srow][skq] = vah;
        *(s8v*)&Asl[srow][skq] = val;
        *(s8v*)&Bsh[srow][skq] = vbh;
        *(s8v*)&Bsl[srow][skq] = vbl;
        __syncthreads();
        s8v a_h[2], a_l[2], b_h[2], b_l[2];
        #pragma unroll
        for (int f = 0; f < 2; ++f){
            a_h[f] = *(const s8v*)&Ash[wm+(f<<4)+lr][lk];
            a_l[f] = *(const s8v*)&Asl[wm+(f<<4)+lr][lk];
            b_h[f] = *(const s8v*)&Bsh[wn+(f<<4)+lr][lk];
            b_l[f] = *(const s8v*)&Bsl[wn+(f<<4)+lr][lk];
        }
        #pragma unroll
        for (int mf = 0; mf < 2; ++mf)
            #pragma unroll
            for (int nf = 0; nf < 2; ++nf){
                acc[mf][nf] = __builtin_amdgcn_mfma_f32_16x16x32_bf16(a_h[mf], b_h[nf], acc[mf][nf], 0,0,0);
                acc[mf][nf] = __builtin_amdgcn_mfma_f32_16x16x32_bf16(a_l[mf], b_h[nf], acc[mf][nf], 0,0,0);
                acc[mf][nf] = __builtin_amdgcn_mfma_f32_16x16x32_bf16(a_h[mf], b_l[nf], acc[mf][nf], 0,0,0);
            }
    }
    const int orr = (lane >> 4) << 2;
    #pragma unroll
    for (int mf = 0; mf < 2; ++mf)
        #pragma unroll
        for (int nf = 0; nf < 2; ++nf)
            #pragma unroll
            for (int r = 0; r < 4; ++r){
                int orow = brow + wm + (mf<<4) + orr + r;
                int ocol = bcol + wn + (nf<<4) + lr;
                u16 h,l; splitf(acc[mf][nf][r], h, l);
                Ch[(size_t)orow*1024 + ocol] = h;
                Cl[(size_t)orow*1024 + ocol] = l;
            }
}

// Mb = (1/6)I + (1/24)A + (1/120)A2 + (1/720)A3   (split pairs in/out), z=3
__global__ __launch_bounds__(256) void ewM_k(const u16* __restrict__ Ab, const u16* __restrict__ A2b,
                                             const u16* __restrict__ A3b, u16* __restrict__ Mbb){
    const int z = blockIdx.z;
    const u16 *Ah=Ab+(size_t)z*2*S, *Al=Ah+S;
    const u16 *A2h=A2b+(size_t)z*2*S, *A2l=A2h+S;
    const u16 *A3h=A3b+(size_t)z*2*S, *A3l=A3h+S;
    u16 *Mh=Mbb+(size_t)z*2*S, *Ml=Mh+S;
    const int idx8 = (blockIdx.x*256 + threadIdx.x) * 8;
    const int r = idx8 >> 10, c0 = idx8 & 1023;
    s8v vah=*(const s8v*)(Ah+idx8), val=*(const s8v*)(Al+idx8);
    s8v v2h=*(const s8v*)(A2h+idx8), v2l=*(const s8v*)(A2l+idx8);
    s8v v3h=*(const s8v*)(A3h+idx8), v3l=*(const s8v*)(A3l+idx8);
    s8v oh, ol;
    #pragma unroll
    for (int i = 0; i < 8; ++i){
        float a  = bf2f((u16)vah[i]) + bf2f((u16)val[i]);
        float a2 = bf2f((u16)v2h[i]) + bf2f((u16)v2l[i]);
        float a3 = bf2f((u16)v3h[i]) + bf2f((u16)v3l[i]);
        float v = (1.0f/24.0f)*a + (1.0f/120.0f)*a2 + (1.0f/720.0f)*a3;
        if (r == c0 + i) v += (1.0f/6.0f);
        u16 h,l; splitf(v,h,l); oh[i]=(short)h; ol[i]=(short)l;
    }
    *(s8v*)(Mh+idx8)=oh; *(s8v*)(Ml+idx8)=ol;
}

// E = I + A + A2/2 + T   (split pairs in/out), z=3
__global__ __launch_bounds__(256) void ewE_k(const u16* __restrict__ Ab, const u16* __restrict__ A2b,
                                             const u16* __restrict__ Tb, u16* __restrict__ Eb){
    const int z = blockIdx.z;
    const u16 *Ah=Ab+(size_t)z*2*S, *Al=Ah+S;
    const u16 *A2h=A2b+(size_t)z*2*S, *A2l=A2h+S;
    const u16 *Th=Tb+(size_t)z*2*S, *Tl=Th+S;
    u16 *Eh=Eb+(size_t)z*2*S, *El=Eh+S;
    const int idx8 = (blockIdx.x*256 + threadIdx.x) * 8;
    const int r = idx8 >> 10, c0 = idx8 & 1023;
    s8v vah=*(const s8v*)(Ah+idx8), val=*(const s8v*)(Al+idx8);
    s8v v2h=*(const s8v*)(A2h+idx8), v2l=*(const s8v*)(A2l+idx8);
    s8v vth=*(const s8v*)(Th+idx8), vtl=*(const s8v*)(Tl+idx8);
    s8v oh, ol;
    #pragma unroll
    for (int i = 0; i < 8; ++i){
        float a  = bf2f((u16)vah[i]) + bf2f((u16)val[i]);
        float a2 = bf2f((u16)v2h[i]) + bf2f((u16)v2l[i]);
        float tt = bf2f((u16)vth[i]) + bf2f((u16)vtl[i]);
        float v = a + 0.5f*a2 + tt;
        if (r == c0 + i) v += 1.0f;
        u16 h,l; splitf(v,h,l); oh[i]=(short)h; ol[i]=(short)l;
    }
    *(s8v*)(Eh+idx8)=oh; *(s8v*)(El+idx8)=ol;
}

// Out pair = transpose of input pair (bf16), 64x64 LDS tiles.
__global__ __launch_bounds__(256) void tsplit_k(const u16* __restrict__ Eh, u16* __restrict__ Oth){
    __shared__ u16 Th[64][72], Tl[64][72];
    const u16* El = Eh + S; u16* Otl = Oth + S;
    const int t = threadIdx.x;
    const int row = t >> 2, cq = (t & 3) << 4;
    const int r0 = blockIdx.y << 6, c0 = blockIdx.x << 6;
    const size_t ro = (size_t)(r0+row)*1024 + c0 + cq;
    *(s8v*)&Th[row][cq]   = *(const s8v*)(Eh + ro);
    *(s8v*)&Th[row][cq+8] = *(const s8v*)(Eh + ro + 8);
    *(s8v*)&Tl[row][cq]   = *(const s8v*)(El + ro);
    *(s8v*)&Tl[row][cq+8] = *(const s8v*)(El + ro + 8);
    __syncthreads();
    s8v a,b,c,d;
    #pragma unroll
    for (int i = 0; i < 8; ++i){
        a[i] = (short)Th[cq+i][row];   b[i] = (short)Th[cq+8+i][row];
        c[i] = (short)Tl[cq+i][row];   d[i] = (short)Tl[cq+8+i][row];
    }
    const size_t wo = (size_t)(c0+row)*1024 + r0 + cq;
    *(s8v*)(Oth + wo)     = a;
    *(s8v*)(Oth + wo + 8) = b;
    *(s8v*)(Otl + wo)     = c;
    *(s8v*)(Otl + wo + 8) = d;
}

// X (fp32) -> bf16 split pair
__global__ __launch_bounds__(256) void xsplit_k(const float* __restrict__ X, u16* __restrict__ Xh,
                                                u16* __restrict__ Xl, int hionly){
    const size_t idx8 = ((size_t)blockIdx.x*256 + threadIdx.x)*8;
    float4 v0 = *(const float4*)(X+idx8);
    float4 v1 = *(const float4*)(X+idx8+4);
    float xs[8] = {v0.x,v0.y,v0.z,v0.w,v1.x,v1.y,v1.z,v1.w};
    s8v h,l;
    #pragma unroll
    for (int i = 0; i < 8; ++i){ u16 hh,ll; splitf(xs[i],hh,ll); h[i]=(short)hh; l[i]=(short)ll; }
    *(s8v*)(Xh+idx8) = h;
    if (!hionly) *(s8v*)(Xl+idx8) = l;
}

// Y[16384,1024] = X * R.  B staged from RT = R^T split pair.
// XMODE 0: X from bf16 pair (Xh, Xh+16S); 1: Xh only; 2: convert from fp32 on the fly.
template<int XMODE>
__global__ __launch_bounds__(256) void gemm_big_k(const void* __restrict__ Xv, const u16* __restrict__ Rth,
                                                  float* __restrict__ Y){
    __shared__ u16 Xsh[128][40], Xsl[128][40], Bsh[128][40], Bsl[128][40];
    const u16* Rtl = Rth + S;
    const int t = threadIdx.x;
    const int brow = blockIdx.y << 7, bcol = blockIdx.x << 7;
    const int srow = t >> 1, shalf = (t & 1) << 4;
    const int lane = t & 63, w = t >> 6;
    const int wm = (w >> 1) << 6, wn = (w & 1) << 6;
    const int lr = lane & 15, lk = (lane >> 4) << 3;
    f4v acc[4][4] = {};
    for (int k0 = 0; k0 < 1024; k0 += 32){
        s8v xh0, xh1, xl0, xl1;
        if (XMODE == 2){
            const float* X = (const float*)Xv;
            const float* p = X + (size_t)(brow+srow)*1024 + k0 + shalf;
            float4 f0 = *(const float4*)(p), f1 = *(const float4*)(p+4);
            float4 f2 = *(const float4*)(p+8), f3 = *(const float4*)(p+12);
            float xs[16] = {f0.x,f0.y,f0.z,f0.w,f1.x,f1.y,f1.z,f1.w,
                            f2.x,f2.y,f2.z,f2.w,f3.x,f3.y,f3.z,f3.w};
            #pragma unroll
            for (int i = 0; i < 8; ++i){
                u16 h,l; splitf(xs[i],h,l);   xh0[i]=(short)h; xl0[i]=(short)l;
                u16 h2,l2; splitf(xs[i+8],h2,l2); xh1[i]=(short)h2; xl1[i]=(short)l2;
            }
        } else {
            const u16* Xh = (const u16*)Xv;
            const size_t xo = (size_t)(brow+srow)*1024 + k0 + shalf;
            xh0 = *(const s8v*)(Xh + xo);
            xh1 = *(const s8v*)(Xh + xo + 8);
            if (XMODE == 0){
                const u16* Xl = Xh + (size_t)16*S;
                xl0 = *(const s8v*)(Xl + xo);
                xl1 = *(const s8v*)(Xl + xo + 8);
            }
        }
        const size_t bo = (size_t)(bcol+srow)*1024 + k0 + shalf;
        s8v bh0 = *(const s8v*)(Rth + bo), bh1 = *(const s8v*)(Rth + bo + 8);
        s8v bl0 = *(const s8v*)(Rtl + bo), bl1 = *(const s8v*)(Rtl + bo + 8);
        __syncthreads();
        *(s8v*)&Xsh[srow][shalf]   = xh0;
        *(s8v*)&Xsh[srow][shalf+8] = xh1;
        if (XMODE != 1){
            *(s8v*)&Xsl[srow][shalf]   = xl0;
            *(s8v*)&Xsl[srow][shalf+8] = xl1;
        }
        *(s8v*)&Bsh[srow][shalf]   = bh0;
        *(s8v*)&Bsh[srow][shalf+8] = bh1;
        *(s8v*)&Bsl[srow][shalf]   = bl0;
        *(s8v*)&Bsl[srow][shalf+8] = bl1;
        __syncthreads();
        s8v bhf[4], blf[4];
        #pragma unroll
        for (int nf = 0; nf < 4; ++nf){
            bhf[nf] = *(const s8v*)&Bsh[wn+(nf<<4)+lr][lk];
            blf[nf] = *(const s8v*)&Bsl[wn+(nf<<4)+lr][lk];
        }
        #pragma unroll
        for (int mf = 0; mf < 4; ++mf){
            s8v ah = *(const s8v*)&Xsh[wm+(mf<<4)+lr][lk];
            s8v al;
            if (XMODE != 1) al = *(const s8v*)&Xsl[wm+(mf<<4)+lr][lk];
            #pragma unroll
            for (int nf = 0; nf < 4; ++nf){
                acc[mf][nf] = __builtin_amdgcn_mfma_f32_16x16x32_bf16(ah, bhf[nf], acc[mf][nf], 0,0,0);
                if (XMODE != 1)
                    acc[mf][nf] = __builtin_amdgcn_mfma_f32_16x16x32_bf16(al, bhf[nf], acc[mf][nf], 0,0,0);
                acc[mf][nf] = __builtin_amdgcn_mfma_f32_16x16x32_bf16(ah, blf[nf], acc[mf][nf], 0,0,0);
            }
        }
    }
    const int orr = (lane >> 4) << 2;
    #pragma unroll
    for (int mf = 0; mf < 4; ++mf)
        #pragma unroll
        for (int nf = 0; nf < 4; ++nf)
            #pragma unroll
            for (int r = 0; r < 4; ++r){
                int orow = brow + wm + (mf<<4) + orr + r;
                int ocol = bcol + wn + (nf<<4) + lr;
                Y[(size_t)orow*1024 + ocol] = acc[mf][nf][r];
            }
}

extern "C" void kernel_launch(void* const* d_in, const int* in_sizes, int n_in,
                              void* d_out, int out_size, void* d_ws, size_t ws_size,
                              hipStream_t stream) {
    const float* X = (const float*)d_in[0];   // [16384,1024] fp32
    const float* G = (const float*)d_in[1];   // [3,1024,1024] fp32
    float* out = (float*)d_out;
    u16* ob = (u16*)d_out;                    // 16 pair-slots of 2*S u16 each
    auto slot = [&](int i){ return ob + (size_t)i*2*S; };
    u16* RT = (u16*)d_ws;                     // R^T split pair (4 MB)
    u16* Xh = RT + (size_t)2*S;               // X hi (32 MB), lo at +16S (32 MB)

    dim3 b(256);
    // slots: A:0-2  A2:3-5  A3:6-8  Mb:9-11  T:12-14  E:9-11  E2t:15  M1:0
    skew_split_k<<<dim3(16,16,3), b, 0, stream>>>(G, slot(0));
    gemm64_k<<<dim3(16,16,3), b, 0, stream>>>(slot(0), slot(0), slot(3), 1);   // A2 = A*A   (Bt=-A)
    gemm64_k<<<dim3(16,16,3), b, 0, stream>>>(slot(3), slot(0), slot(6), 1);   // A3 = A2*A  (Bt=-A)
    ewM_k<<<dim3(512,1,3), b, 0, stream>>>(slot(0), slot(3), slot(6), slot(9));
    gemm64_k<<<dim3(16,16,3), b, 0, stream>>>(slot(9), slot(6), slot(12), 1);  // T = Mb*A3  (Bt=-A3)
    ewE_k<<<dim3(512,1,3), b, 0, stream>>>(slot(0), slot(3), slot(12), slot(9)); // E -> 9,10,11
    tsplit_k<<<dim3(16,16), b, 0, stream>>>(slot(11), slot(15));               // E2t
    gemm64_k<<<dim3(16,16,1), b, 0, stream>>>(slot(15), slot(10), slot(0), 0); // M1 = E2^T*E1^T (Bt=E1)
    gemm64_k<<<dim3(16,16,1), b, 0, stream>>>(slot(0), slot(9), RT, 0);        // RT = M1*E0^T   (Bt=E0)

    const size_t need_full = (size_t)34*S*2;  // RT + Xh + Xl
    const size_t need_hi   = (size_t)18*S*2;  // RT + Xh
    if (ws_size >= need_full){
        xsplit_k<<<8192, b, 0, stream>>>(X, Xh, Xh + (size_t)16*S, 0);
        gemm_big_k<0><<<dim3(8,128), b, 0, stream>>>(Xh, RT, out);
    } else if (ws_size >= need_hi){
        xsplit_k<<<8192, b, 0, stream>>>(X, Xh, Xh, 1);
        gemm_big_k<1><<<dim3(8,128), b, 0, stream>>>(Xh, RT, out);
    } else {
        gemm_big_k<2><<<dim3(8,128), b, 0, stream>>>(X, RT, out);
    }
}

// Round 3
// 284.127 us; speedup vs baseline: 3.9438x; 1.1607x over previous
//
#include <hip/hip_runtime.h>

#define S 1048576
typedef unsigned short u16;
typedef unsigned int u32;
typedef __attribute__((ext_vector_type(8))) short s8v;   // 8 bf16 (4 VGPRs)
typedef __attribute__((ext_vector_type(4))) float f4v;   // MFMA acc

__device__ __forceinline__ float bf2f(u16 u){
    union { float f; u32 u; } v; v.u = ((u32)u) << 16; return v.f;
}
__device__ __forceinline__ u16 f2bf(float x){
    u32 u = __float_as_uint(x);
    u32 r = (u + 0x7FFFu + ((u >> 16) & 1u)) >> 16;   // RNE
    return (u16)r;
}
__device__ __forceinline__ void splitf(float x, u16& h, u16& l){
    h = f2bf(x);
    l = f2bf(x - bf2f(h));
}
__device__ __forceinline__ float pairf(const u16* H, const u16* L, size_t off){
    return bf2f(H[off]) + bf2f(L[off]);
}

// Fused: blocks [0,768): A_z = 0.5*(G_z - G_z^T) split pair (64x64 tiles, z=bid>>8)
//        blocks [768,...): X fp32 -> bf16 hi only (skipped if grid==768)
__global__ __launch_bounds__(256) void pre_k(const float* __restrict__ G, u16* __restrict__ Abase,
                                             const float* __restrict__ X, u16* __restrict__ Xh){
    __shared__ float Gt[64][65];
    const int bid = blockIdx.x;
    const int t = threadIdx.x;
    if (bid < 768){
        const int bx = bid & 15, by = (bid >> 4) & 15, z = bid >> 8;
        const float* Gz = G + (size_t)z*S;
        u16* Ah = Abase + (size_t)z*2*S;
        u16* Al = Ah + S;
        const int row = t >> 2, cq = (t & 3) << 4;
        const int r0 = by << 6, c0 = bx << 6;
        #pragma unroll
        for (int g = 0; g < 4; ++g){
            float4 v = *(const float4*)(Gz + (size_t)(c0+row)*1024 + r0 + cq + g*4);
            Gt[row][cq+g*4+0]=v.x; Gt[row][cq+g*4+1]=v.y; Gt[row][cq+g*4+2]=v.z; Gt[row][cq+g*4+3]=v.w;
        }
        __syncthreads();
        #pragma unroll
        for (int g = 0; g < 2; ++g){
            const float* p = Gz + (size_t)(r0+row)*1024 + c0 + cq + g*8;
            float4 v0 = *(const float4*)(p);
            float4 v1 = *(const float4*)(p+4);
            float xs[8] = {v0.x,v0.y,v0.z,v0.w,v1.x,v1.y,v1.z,v1.w};
            s8v sh, sl;
            #pragma unroll
            for (int i = 0; i < 8; ++i){
                float gt = Gt[cq + g*8 + i][row];
                u16 h,l; splitf(0.5f*(xs[i]-gt), h, l);
                sh[i] = (short)h; sl[i] = (short)l;
            }
            *(s8v*)(Ah + (size_t)(r0+row)*1024 + c0 + cq + g*8) = sh;
            *(s8v*)(Al + (size_t)(r0+row)*1024 + c0 + cq + g*8) = sl;
        }
    } else {
        const size_t idx8 = ((size_t)(bid-768)*256 + t)*8;
        float4 v0 = *(const float4*)(X+idx8);
        float4 v1 = *(const float4*)(X+idx8+4);
        float xs[8] = {v0.x,v0.y,v0.z,v0.w,v1.x,v1.y,v1.z,v1.w};
        s8v h;
        #pragma unroll
        for (int i = 0; i < 8; ++i) h[i] = (short)f2bf(xs[i]);
        *(s8v*)(Xh+idx8) = h;
    }
}

// C = A * B with split-bf16 MFMA (3 passes). A row-major pair; Bt row-major B^T pair (opt negated).
// 64x64 tile, BK=32, 4 waves, z-batched.
// MODE 0: write C pair.
// MODE 1: write C pair AND Out2 = (1/6)I + (1/24)*Bt_raw + (1/120)*A_op + (1/720)*acc
//         (call with A_op=A2, Bt=A  =>  Out2 = Mb)
// MODE 2: write ONLY Out2 = I + Pa + 0.5*Pa2 + acc   (call computing T=Mb*A3 => Out2 = E)
template<int MODE>
__global__ __launch_bounds__(256) void gemm64_k(const u16* __restrict__ Abase, const u16* __restrict__ Btbase,
                                                u16* __restrict__ Cbase, int negb,
                                                const u16* __restrict__ Pab, const u16* __restrict__ Pa2b,
                                                u16* __restrict__ O2base){
    __shared__ u16 Ash[64][40], Asl[64][40], Bsh[64][40], Bsl[64][40];
    const int z = blockIdx.z;
    const u16* Ah = Abase  + (size_t)z*2*S; const u16* Al = Ah + S;
    const u16* Bh = Btbase + (size_t)z*2*S; const u16* Bl = Bh + S;
    u16* Ch = Cbase + (size_t)z*2*S;        u16* Cl = Ch + S;
    const u16* Pah = Pab + (size_t)z*2*S;   const u16* Pal = Pah + S;
    const u16* P2h = Pa2b + (size_t)z*2*S;  const u16* P2l = P2h + S;
    u16* O2h = O2base + (size_t)z*2*S;      u16* O2l = O2h + S;
    const int t = threadIdx.x;
    const int brow = blockIdx.y << 6, bcol = blockIdx.x << 6;
    const int srow = t >> 2, skq = (t & 3) << 3;
    const int lane = t & 63, w = t >> 6;
    const int wm = (w >> 1) << 5, wn = (w & 1) << 5;
    const int lr = lane & 15, lk = (lane >> 4) << 3;
    const short nm = negb ? (short)0x8000 : (short)0;
    const s8v msk = {nm,nm,nm,nm,nm,nm,nm,nm};
    f4v acc[2][2] = {};
    for (int k0 = 0; k0 < 1024; k0 += 32){
        const size_t ao = (size_t)(brow+srow)*1024 + k0 + skq;
        const size_t bo = (size_t)(bcol+srow)*1024 + k0 + skq;
        s8v vah = *(const s8v*)(Ah + ao);
        s8v val = *(const s8v*)(Al + ao);
        s8v vbh = *(const s8v*)(Bh + bo) ^ msk;
        s8v vbl = *(const s8v*)(Bl + bo) ^ msk;
        __syncthreads();
        *(s8v*)&Ash[srow][skq] = vah;
        *(s8v*)&Asl[srow][skq] = val;
        *(s8v*)&Bsh[srow][skq] = vbh;
        *(s8v*)&Bsl[srow][skq] = vbl;
        __syncthreads();
        s8v a_h[2], a_l[2], b_h[2], b_l[2];
        #pragma unroll
        for (int f = 0; f < 2; ++f){
            a_h[f] = *(const s8v*)&Ash[wm+(f<<4)+lr][lk];
            a_l[f] = *(const s8v*)&Asl[wm+(f<<4)+lr][lk];
            b_h[f] = *(const s8v*)&Bsh[wn+(f<<4)+lr][lk];
            b_l[f] = *(const s8v*)&Bsl[wn+(f<<4)+lr][lk];
        }
        #pragma unroll
        for (int mf = 0; mf < 2; ++mf)
            #pragma unroll
            for (int nf = 0; nf < 2; ++nf){
                acc[mf][nf] = __builtin_amdgcn_mfma_f32_16x16x32_bf16(a_h[mf], b_h[nf], acc[mf][nf], 0,0,0);
                acc[mf][nf] = __builtin_amdgcn_mfma_f32_16x16x32_bf16(a_l[mf], b_h[nf], acc[mf][nf], 0,0,0);
                acc[mf][nf] = __builtin_amdgcn_mfma_f32_16x16x32_bf16(a_h[mf], b_l[nf], acc[mf][nf], 0,0,0);
            }
    }
    const int orr = (lane >> 4) << 2;
    #pragma unroll
    for (int mf = 0; mf < 2; ++mf)
        #pragma unroll
        for (int nf = 0; nf < 2; ++nf)
            #pragma unroll
            for (int r = 0; r < 4; ++r){
                const int orow = brow + wm + (mf<<4) + orr + r;
                const int ocol = bcol + wn + (nf<<4) + lr;
                const size_t off = (size_t)orow*1024 + ocol;
                const float av = acc[mf][nf][r];
                if (MODE == 0 || MODE == 1){
                    u16 h,l; splitf(av, h, l);
                    Ch[off] = h; Cl[off] = l;
                }
                if (MODE == 1){
                    // Bt_raw holds A (unnegated), A_op holds A2
                    float a  = pairf(Bh, Bl, off);
                    float a2 = pairf(Ah, Al, off);
                    float mb = (1.0f/24.0f)*a + (1.0f/120.0f)*a2 + (1.0f/720.0f)*av
                             + (orow == ocol ? (1.0f/6.0f) : 0.0f);
                    u16 h,l; splitf(mb, h, l);
                    O2h[off] = h; O2l[off] = l;
                }
                if (MODE == 2){
                    float a  = pairf(Pah, Pal, off);
                    float a2 = pairf(P2h, P2l, off);
                    float e = av + a + 0.5f*a2 + (orow == ocol ? 1.0f : 0.0f);
                    u16 h,l; splitf(e, h, l);
                    O2h[off] = h; O2l[off] = l;
                }
            }
}

// Out pair = transpose of input pair (bf16), 64x64 LDS tiles.
__global__ __launch_bounds__(256) void tsplit_k(const u16* __restrict__ Eh, u16* __restrict__ Oth){
    __shared__ u16 Th[64][72], Tl[64][72];
    const u16* El = Eh + S; u16* Otl = Oth + S;
    const int t = threadIdx.x;
    const int row = t >> 2, cq = (t & 3) << 4;
    const int r0 = blockIdx.y << 6, c0 = blockIdx.x << 6;
    const size_t ro = (size_t)(r0+row)*1024 + c0 + cq;
    *(s8v*)&Th[row][cq]   = *(const s8v*)(Eh + ro);
    *(s8v*)&Th[row][cq+8] = *(const s8v*)(Eh + ro + 8);
    *(s8v*)&Tl[row][cq]   = *(const s8v*)(El + ro);
    *(s8v*)&Tl[row][cq+8] = *(const s8v*)(El + ro + 8);
    __syncthreads();
    s8v a,b,c,d;
    #pragma unroll
    for (int i = 0; i < 8; ++i){
        a[i] = (short)Th[cq+i][row];   b[i] = (short)Th[cq+8+i][row];
        c[i] = (short)Tl[cq+i][row];   d[i] = (short)Tl[cq+8+i][row];
    }
    const size_t wo = (size_t)(c0+row)*1024 + r0 + cq;
    *(s8v*)(Oth + wo)     = a;
    *(s8v*)(Oth + wo + 8) = b;
    *(s8v*)(Otl + wo)     = c;
    *(s8v*)(Otl + wo + 8) = d;
}

// Y[16384,1024] = X * R.  B from RT = R^T split pair; 2 MFMA passes (Xh*Bh + Xh*Bl).
// XMODE 1: X preconverted bf16 hi; 2: fp32 converted on the fly.
template<int XMODE>
__global__ __launch_bounds__(256) void gemm_big_k(const void* __restrict__ Xv, const u16* __restrict__ Rth,
                                                  float* __restrict__ Y){
    __shared__ u16 Xsh[128][40], Bsh[128][40], Bsl[128][40];
    const u16* Rtl = Rth + S;
    const int t = threadIdx.x;
    const int brow = blockIdx.y << 7, bcol = blockIdx.x << 7;
    const int srow = t >> 1, shalf = (t & 1) << 4;
    const int lane = t & 63, w = t >> 6;
    const int wm = (w >> 1) << 6, wn = (w & 1) << 6;
    const int lr = lane & 15, lk = (lane >> 4) << 3;
    f4v acc[4][4] = {};
    for (int k0 = 0; k0 < 1024; k0 += 32){
        s8v xh0, xh1;
        if (XMODE == 2){
            const float* X = (const float*)Xv;
            const float* p = X + (size_t)(brow+srow)*1024 + k0 + shalf;
            float4 f0 = *(const float4*)(p), f1 = *(const float4*)(p+4);
            float4 f2 = *(const float4*)(p+8), f3 = *(const float4*)(p+12);
            float xs[16] = {f0.x,f0.y,f0.z,f0.w,f1.x,f1.y,f1.z,f1.w,
                            f2.x,f2.y,f2.z,f2.w,f3.x,f3.y,f3.z,f3.w};
            #pragma unroll
            for (int i = 0; i < 8; ++i){
                xh0[i] = (short)f2bf(xs[i]);
                xh1[i] = (short)f2bf(xs[i+8]);
            }
        } else {
            const u16* Xh = (const u16*)Xv;
            const size_t xo = (size_t)(brow+srow)*1024 + k0 + shalf;
            xh0 = *(const s8v*)(Xh + xo);
            xh1 = *(const s8v*)(Xh + xo + 8);
        }
        const size_t bo = (size_t)(bcol+srow)*1024 + k0 + shalf;
        s8v bh0 = *(const s8v*)(Rth + bo), bh1 = *(const s8v*)(Rth + bo + 8);
        s8v bl0 = *(const s8v*)(Rtl + bo), bl1 = *(const s8v*)(Rtl + bo + 8);
        __syncthreads();
        *(s8v*)&Xsh[srow][shalf]   = xh0;
        *(s8v*)&Xsh[srow][shalf+8] = xh1;
        *(s8v*)&Bsh[srow][shalf]   = bh0;
        *(s8v*)&Bsh[srow][shalf+8] = bh1;
        *(s8v*)&Bsl[srow][shalf]   = bl0;
        *(s8v*)&Bsl[srow][shalf+8] = bl1;
        __syncthreads();
        s8v bhf[4], blf[4];
        #pragma unroll
        for (int nf = 0; nf < 4; ++nf){
            bhf[nf] = *(const s8v*)&Bsh[wn+(nf<<4)+lr][lk];
            blf[nf] = *(const s8v*)&Bsl[wn+(nf<<4)+lr][lk];
        }
        #pragma unroll
        for (int mf = 0; mf < 4; ++mf){
            s8v ah = *(const s8v*)&Xsh[wm+(mf<<4)+lr][lk];
            #pragma unroll
            for (int nf = 0; nf < 4; ++nf){
                acc[mf][nf] = __builtin_amdgcn_mfma_f32_16x16x32_bf16(ah, bhf[nf], acc[mf][nf], 0,0,0);
                acc[mf][nf] = __builtin_amdgcn_mfma_f32_16x16x32_bf16(ah, blf[nf], acc[mf][nf], 0,0,0);
            }
        }
    }
    const int orr = (lane >> 4) << 2;
    #pragma unroll
    for (int mf = 0; mf < 4; ++mf)
        #pragma unroll
        for (int nf = 0; nf < 4; ++nf)
            #pragma unroll
            for (int r = 0; r < 4; ++r){
                int orow = brow + wm + (mf<<4) + orr + r;
                int ocol = bcol + wn + (nf<<4) + lr;
                Y[(size_t)orow*1024 + ocol] = acc[mf][nf][r];
            }
}

extern "C" void kernel_launch(void* const* d_in, const int* in_sizes, int n_in,
                              void* d_out, int out_size, void* d_ws, size_t ws_size,
                              hipStream_t stream) {
    const float* X = (const float*)d_in[0];   // [16384,1024] fp32
    const float* G = (const float*)d_in[1];   // [3,1024,1024] fp32
    float* out = (float*)d_out;
    u16* ob = (u16*)d_out;                    // 16 pair-slots of 2*S u16 each
    auto slot = [&](int i){ return ob + (size_t)i*2*S; };
    u16* RT = (u16*)d_ws;                     // R^T split pair (4 MB)
    u16* Xh = RT + (size_t)2*S;               // X hi bf16 (32 MB)
    const bool ws_ok = ws_size >= (size_t)36*S; // bytes: 2S*2 (RT) + 16S*2 (Xh)

    dim3 b(256);
    // slots: A:0-2  A2:3-5  A3:6-8  Mb:9-11  E:12-14  E2t:15  M1:0
    pre_k<<<dim3(ws_ok ? 8960 : 768), b, 0, stream>>>(G, slot(0), X, Xh);
    gemm64_k<0><<<dim3(16,16,3), b, 0, stream>>>(slot(0), slot(0), slot(3), 1,
                                                 slot(0), slot(0), slot(3));          // A2 = A*A
    gemm64_k<1><<<dim3(16,16,3), b, 0, stream>>>(slot(3), slot(0), slot(6), 1,
                                                 slot(0), slot(3), slot(9));          // A3 + Mb
    gemm64_k<2><<<dim3(16,16,3), b, 0, stream>>>(slot(9), slot(6), slot(9), 1,
                                                 slot(0), slot(3), slot(12));         // E = I+A+A2/2+Mb*A3
    tsplit_k<<<dim3(16,16), b, 0, stream>>>(slot(14), slot(15));                      // E2^T
    gemm64_k<0><<<dim3(16,16,1), b, 0, stream>>>(slot(15), slot(13), slot(0), 0,
                                                 slot(0), slot(0), slot(0));          // M1 = E2^T*E1^T
    gemm64_k<0><<<dim3(16,16,1), b, 0, stream>>>(slot(0), slot(12), RT, 0,
                                                 slot(0), slot(0), RT);               // RT = M1*E0^T
    if (ws_ok)
        gemm_big_k<1><<<dim3(8,128), b, 0, stream>>>(Xh, RT, out);
    else
        gemm_big_k<2><<<dim3(8,128), b, 0, stream>>>(X, RT, out);
}

// Round 4
// 242.624 us; speedup vs baseline: 4.6184x; 1.1711x over previous
//
#include <hip/hip_runtime.h>

#define S 1048576
typedef unsigned short u16;
typedef unsigned int u32;
typedef __attribute__((ext_vector_type(8))) short s8v;   // 8 bf16 (4 VGPRs)
typedef __attribute__((ext_vector_type(4))) float f4v;   // MFMA acc

__device__ __forceinline__ float bf2f(u16 u){
    union { float f; u32 u; } v; v.u = ((u32)u) << 16; return v.f;
}
__device__ __forceinline__ u16 f2bf(float x){
    u32 u = __float_as_uint(x);
    u32 r = (u + 0x7FFFu + ((u >> 16) & 1u)) >> 16;   // RNE
    return (u16)r;
}
__device__ __forceinline__ void splitf(float x, u16& h, u16& l){
    h = f2bf(x);
    l = f2bf(x - bf2f(h));
}
__device__ __forceinline__ float pairf(const u16* H, const u16* L, size_t off){
    return bf2f(H[off]) + bf2f(L[off]);
}
// XOR-swizzled LDS index (u16 units): 128-byte rows of 8 16B chunks, chunk ^= row&7
__device__ __forceinline__ int sidx(int r, int c){ return (r<<6) + (((c) ^ (r&7))<<3); }

// Fused: blocks [0,768): A_z = 0.5*(G_z - G_z^T) split pair (64x64 tiles, z=bid>>8)
//        blocks [768,...): X fp32 -> bf16 hi only (skipped if grid==768)
__global__ __launch_bounds__(256) void pre_k(const float* __restrict__ G, u16* __restrict__ Abase,
                                             const float* __restrict__ X, u16* __restrict__ Xh){
    __shared__ float Gt[64][65];
    const int bid = blockIdx.x;
    const int t = threadIdx.x;
    if (bid < 768){
        const int bx = bid & 15, by = (bid >> 4) & 15, z = bid >> 8;
        const float* Gz = G + (size_t)z*S;
        u16* Ah = Abase + (size_t)z*2*S;
        u16* Al = Ah + S;
        const int row = t >> 2, cq = (t & 3) << 4;
        const int r0 = by << 6, c0 = bx << 6;
        #pragma unroll
        for (int g = 0; g < 4; ++g){
            float4 v = *(const float4*)(Gz + (size_t)(c0+row)*1024 + r0 + cq + g*4);
            Gt[row][cq+g*4+0]=v.x; Gt[row][cq+g*4+1]=v.y; Gt[row][cq+g*4+2]=v.z; Gt[row][cq+g*4+3]=v.w;
        }
        __syncthreads();
        #pragma unroll
        for (int g = 0; g < 2; ++g){
            const float* p = Gz + (size_t)(r0+row)*1024 + c0 + cq + g*8;
            float4 v0 = *(const float4*)(p);
            float4 v1 = *(const float4*)(p+4);
            float xs[8] = {v0.x,v0.y,v0.z,v0.w,v1.x,v1.y,v1.z,v1.w};
            s8v sh, sl;
            #pragma unroll
            for (int i = 0; i < 8; ++i){
                float gt = Gt[cq + g*8 + i][row];
                u16 h,l; splitf(0.5f*(xs[i]-gt), h, l);
                sh[i] = (short)h; sl[i] = (short)l;
            }
            *(s8v*)(Ah + (size_t)(r0+row)*1024 + c0 + cq + g*8) = sh;
            *(s8v*)(Al + (size_t)(r0+row)*1024 + c0 + cq + g*8) = sl;
        }
    } else {
        const size_t idx8 = ((size_t)(bid-768)*256 + t)*8;
        float4 v0 = *(const float4*)(X+idx8);
        float4 v1 = *(const float4*)(X+idx8+4);
        float xs[8] = {v0.x,v0.y,v0.z,v0.w,v1.x,v1.y,v1.z,v1.w};
        s8v h;
        #pragma unroll
        for (int i = 0; i < 8; ++i) h[i] = (short)f2bf(xs[i]);
        *(s8v*)(Xh+idx8) = h;
    }
}

// C = A * B with split-bf16 MFMA (3 passes). A row-major pair; Bt row-major B^T pair (opt negated).
// 64x64 tile, BK=64, XOR-swizzled LDS, software-pipelined staging, 4 waves, z-batched.
// MODE 0: write C pair.
// MODE 1: write C pair AND Out2 = (1/6)I + (1/24)*Bt_raw + (1/120)*A_op + (1/720)*acc
// MODE 2: write ONLY Out2 = I + Pa + 0.5*Pa2 + acc
template<int MODE>
__global__ __launch_bounds__(256) void gemm64_k(const u16* __restrict__ Abase, const u16* __restrict__ Btbase,
                                                u16* __restrict__ Cbase, int negb,
                                                const u16* __restrict__ Pab, const u16* __restrict__ Pa2b,
                                                u16* __restrict__ O2base){
    __shared__ u16 Ash[64*64], Asl[64*64], Bsh[64*64], Bsl[64*64];
    const int z = blockIdx.z;
    const u16* Ah = Abase  + (size_t)z*2*S; const u16* Al = Ah + S;
    const u16* Bh = Btbase + (size_t)z*2*S; const u16* Bl = Bh + S;
    u16* Ch = Cbase + (size_t)z*2*S;        u16* Cl = Ch + S;
    const u16* Pah = Pab + (size_t)z*2*S;   const u16* Pal = Pah + S;
    const u16* P2h = Pa2b + (size_t)z*2*S;  const u16* P2l = P2h + S;
    u16* O2h = O2base + (size_t)z*2*S;      u16* O2l = O2h + S;
    const int t = threadIdx.x;
    const int brow = blockIdx.y << 6, bcol = blockIdx.x << 6;
    const int sr = t >> 2, cb = (t & 3) << 1;      // staging: row, 2 chunks
    const int lane = t & 63, w = t >> 6;
    const int wm = (w >> 1) << 5, wn = (w & 1) << 5;
    const int lr = lane & 15, g = lane >> 4;       // frag: k-group
    const short nm = negb ? (short)0x8000 : (short)0;
    const s8v msk = {nm,nm,nm,nm,nm,nm,nm,nm};
    s8v s_ah[2], s_al[2], s_bh[2], s_bl[2];
    #pragma unroll
    for (int i = 0; i < 2; ++i){
        const size_t ao = (size_t)(brow+sr)*1024 + ((cb+i)<<3);
        const size_t bo = (size_t)(bcol+sr)*1024 + ((cb+i)<<3);
        s_ah[i] = *(const s8v*)(Ah + ao);
        s_al[i] = *(const s8v*)(Al + ao);
        s_bh[i] = *(const s8v*)(Bh + bo) ^ msk;
        s_bl[i] = *(const s8v*)(Bl + bo) ^ msk;
    }
    f4v acc[2][2] = {};
    for (int k0 = 0; k0 < 1024; k0 += 64){
        __syncthreads();
        #pragma unroll
        for (int i = 0; i < 2; ++i){
            const int si = sidx(sr, cb+i);
            *(s8v*)&Ash[si] = s_ah[i];
            *(s8v*)&Asl[si] = s_al[i];
            *(s8v*)&Bsh[si] = s_bh[i];
            *(s8v*)&Bsl[si] = s_bl[i];
        }
        __syncthreads();
        if (k0 < 960){
            #pragma unroll
            for (int i = 0; i < 2; ++i){
                const size_t ao = (size_t)(brow+sr)*1024 + k0 + 64 + ((cb+i)<<3);
                const size_t bo = (size_t)(bcol+sr)*1024 + k0 + 64 + ((cb+i)<<3);
                s_ah[i] = *(const s8v*)(Ah + ao);
                s_al[i] = *(const s8v*)(Al + ao);
                s_bh[i] = *(const s8v*)(Bh + bo) ^ msk;
                s_bl[i] = *(const s8v*)(Bl + bo) ^ msk;
            }
        }
        #pragma unroll
        for (int ks = 0; ks < 2; ++ks){
            const int ch = (ks << 2) + g;
            s8v a_h[2], a_l[2], b_h[2], b_l[2];
            #pragma unroll
            for (int f = 0; f < 2; ++f){
                a_h[f] = *(const s8v*)&Ash[sidx(wm+(f<<4)+lr, ch)];
                a_l[f] = *(const s8v*)&Asl[sidx(wm+(f<<4)+lr, ch)];
                b_h[f] = *(const s8v*)&Bsh[sidx(wn+(f<<4)+lr, ch)];
                b_l[f] = *(const s8v*)&Bsl[sidx(wn+(f<<4)+lr, ch)];
            }
            #pragma unroll
            for (int mf = 0; mf < 2; ++mf)
                #pragma unroll
                for (int nf = 0; nf < 2; ++nf){
                    acc[mf][nf] = __builtin_amdgcn_mfma_f32_16x16x32_bf16(a_h[mf], b_h[nf], acc[mf][nf], 0,0,0);
                    acc[mf][nf] = __builtin_amdgcn_mfma_f32_16x16x32_bf16(a_l[mf], b_h[nf], acc[mf][nf], 0,0,0);
                    acc[mf][nf] = __builtin_amdgcn_mfma_f32_16x16x32_bf16(a_h[mf], b_l[nf], acc[mf][nf], 0,0,0);
                }
        }
    }
    const int orr = (lane >> 4) << 2;
    #pragma unroll
    for (int mf = 0; mf < 2; ++mf)
        #pragma unroll
        for (int nf = 0; nf < 2; ++nf)
            #pragma unroll
            for (int r = 0; r < 4; ++r){
                const int orow = brow + wm + (mf<<4) + orr + r;
                const int ocol = bcol + wn + (nf<<4) + lr;
                const size_t off = (size_t)orow*1024 + ocol;
                const float av = acc[mf][nf][r];
                if (MODE == 0 || MODE == 1){
                    u16 h,l; splitf(av, h, l);
                    Ch[off] = h; Cl[off] = l;
                }
                if (MODE == 1){
                    float a  = pairf(Bh, Bl, off);
                    float a2 = pairf(Ah, Al, off);
                    float mb = (1.0f/24.0f)*a + (1.0f/120.0f)*a2 + (1.0f/720.0f)*av
                             + (orow == ocol ? (1.0f/6.0f) : 0.0f);
                    u16 h,l; splitf(mb, h, l);
                    O2h[off] = h; O2l[off] = l;
                }
                if (MODE == 2){
                    float a  = pairf(Pah, Pal, off);
                    float a2 = pairf(P2h, P2l, off);
                    float e = av + a + 0.5f*a2 + (orow == ocol ? 1.0f : 0.0f);
                    u16 h,l; splitf(e, h, l);
                    O2h[off] = h; O2l[off] = l;
                }
            }
}

// Out pair = transpose of input pair (bf16), 64x64 LDS tiles.
__global__ __launch_bounds__(256) void tsplit_k(const u16* __restrict__ Eh, u16* __restrict__ Oth){
    __shared__ u16 Th[64][72], Tl[64][72];
    const u16* El = Eh + S; u16* Otl = Oth + S;
    const int t = threadIdx.x;
    const int row = t >> 2, cq = (t & 3) << 4;
    const int r0 = blockIdx.y << 6, c0 = blockIdx.x << 6;
    const size_t ro = (size_t)(r0+row)*1024 + c0 + cq;
    *(s8v*)&Th[row][cq]   = *(const s8v*)(Eh + ro);
    *(s8v*)&Th[row][cq+8] = *(const s8v*)(Eh + ro + 8);
    *(s8v*)&Tl[row][cq]   = *(const s8v*)(El + ro);
    *(s8v*)&Tl[row][cq+8] = *(const s8v*)(El + ro + 8);
    __syncthreads();
    s8v a,b,c,d;
    #pragma unroll
    for (int i = 0; i < 8; ++i){
        a[i] = (short)Th[cq+i][row];   b[i] = (short)Th[cq+8+i][row];
        c[i] = (short)Tl[cq+i][row];   d[i] = (short)Tl[cq+8+i][row];
    }
    const size_t wo = (size_t)(c0+row)*1024 + r0 + cq;
    *(s8v*)(Oth + wo)     = a;
    *(s8v*)(Oth + wo + 8) = b;
    *(s8v*)(Otl + wo)     = c;
    *(s8v*)(Otl + wo + 8) = d;
}

// Y[16384,1024] = X * R.  B from RT = R^T split pair; 2 MFMA passes (Xh*Bh + Xh*Bl).
// 128x128 tile, BK=64, XOR-swizzled LDS, XCD-chunked block swizzle, pipelined staging.
// XMODE 1: X preconverted bf16 hi; 2: fp32 converted on the fly.
template<int XMODE>
__global__ __launch_bounds__(256) void gemm_big_k(const void* __restrict__ Xv, const u16* __restrict__ Rth,
                                                  float* __restrict__ Y){
    __shared__ u16 Xs[128*64], Bhs[128*64], Bls[128*64];
    const u16* Rtl = Rth + S;
    const int bid = blockIdx.x;
    const int swz = (bid & 7)*128 + (bid >> 3);    // chunked XCD swizzle (bijective, 1024 blocks)
    const int bx = swz & 7, by = swz >> 3;
    const int brow = by << 7, bcol = bx << 7;
    const int t = threadIdx.x;
    const int sr = t >> 1, cb = (t & 1) << 2;      // staging: row 0..127, 4 chunks
    const int lane = t & 63, w = t >> 6;
    const int wm = (w >> 1) << 6, wn = (w & 1) << 6;
    const int lr = lane & 15, g = lane >> 4;
    s8v xr[4], bhr[4], blr[4];
    auto load_tile = [&](int k0){
        #pragma unroll
        for (int i = 0; i < 4; ++i){
            const size_t bo = (size_t)(bcol+sr)*1024 + k0 + ((cb+i)<<3);
            bhr[i] = *(const s8v*)(Rth + bo);
            blr[i] = *(const s8v*)(Rtl + bo);
        }
        if (XMODE == 2){
            const float* X = (const float*)Xv;
            #pragma unroll
            for (int i = 0; i < 4; ++i){
                const float* p = X + (size_t)(brow+sr)*1024 + k0 + ((cb+i)<<3);
                float4 f0 = *(const float4*)(p), f1 = *(const float4*)(p+4);
                float xs[8] = {f0.x,f0.y,f0.z,f0.w,f1.x,f1.y,f1.z,f1.w};
                #pragma unroll
                for (int j = 0; j < 8; ++j) xr[i][j] = (short)f2bf(xs[j]);
            }
        } else {
            const u16* Xh = (const u16*)Xv;
            #pragma unroll
            for (int i = 0; i < 4; ++i)
                xr[i] = *(const s8v*)(Xh + (size_t)(brow+sr)*1024 + k0 + ((cb+i)<<3));
        }
    };
    load_tile(0);
    f4v acc[4][4] = {};
    for (int k0 = 0; k0 < 1024; k0 += 64){
        __syncthreads();
        #pragma unroll
        for (int i = 0; i < 4; ++i){
            const int si = sidx(sr, cb+i);
            *(s8v*)&Xs[si]  = xr[i];
            *(s8v*)&Bhs[si] = bhr[i];
            *(s8v*)&Bls[si] = blr[i];
        }
        __syncthreads();
        if (k0 < 960) load_tile(k0 + 64);
        #pragma unroll
        for (int ks = 0; ks < 2; ++ks){
            const int ch = (ks << 2) + g;
            s8v bhf[4], blf[4];
            #pragma unroll
            for (int nf = 0; nf < 4; ++nf){
                bhf[nf] = *(const s8v*)&Bhs[sidx(wn+(nf<<4)+lr, ch)];
                blf[nf] = *(const s8v*)&Bls[sidx(wn+(nf<<4)+lr, ch)];
            }
            #pragma unroll
            for (int mf = 0; mf < 4; ++mf){
                s8v ah = *(const s8v*)&Xs[sidx(wm+(mf<<4)+lr, ch)];
                #pragma unroll
                for (int nf = 0; nf < 4; ++nf){
                    acc[mf][nf] = __builtin_amdgcn_mfma_f32_16x16x32_bf16(ah, bhf[nf], acc[mf][nf], 0,0,0);
                    acc[mf][nf] = __builtin_amdgcn_mfma_f32_16x16x32_bf16(ah, blf[nf], acc[mf][nf], 0,0,0);
                }
            }
        }
    }
    const int orr = (lane >> 4) << 2;
    #pragma unroll
    for (int mf = 0; mf < 4; ++mf)
        #pragma unroll
        for (int nf = 0; nf < 4; ++nf)
            #pragma unroll
            for (int r = 0; r < 4; ++r){
                int orow = brow + wm + (mf<<4) + orr + r;
                int ocol = bcol + wn + (nf<<4) + lr;
                Y[(size_t)orow*1024 + ocol] = acc[mf][nf][r];
            }
}

extern "C" void kernel_launch(void* const* d_in, const int* in_sizes, int n_in,
                              void* d_out, int out_size, void* d_ws, size_t ws_size,
                              hipStream_t stream) {
    const float* X = (const float*)d_in[0];   // [16384,1024] fp32
    const float* G = (const float*)d_in[1];   // [3,1024,1024] fp32
    float* out = (float*)d_out;
    u16* ob = (u16*)d_out;                    // 16 pair-slots of 2*S u16 each
    auto slot = [&](int i){ return ob + (size_t)i*2*S; };
    u16* RT = (u16*)d_ws;                     // R^T split pair (4 MB)
    u16* Xh = RT + (size_t)2*S;               // X hi bf16 (32 MB)
    const bool ws_ok = ws_size >= (size_t)36*S; // bytes: 2S*2 (RT) + 16S*2 (Xh)

    dim3 b(256);
    // slots: A:0-2  A2:3-5  A3:6-8  Mb:9-11  E:12-14  E2t:15  M1:0
    pre_k<<<dim3(ws_ok ? 8960 : 768), b, 0, stream>>>(G, slot(0), X, Xh);
    gemm64_k<0><<<dim3(16,16,3), b, 0, stream>>>(slot(0), slot(0), slot(3), 1,
                                                 slot(0), slot(0), slot(3));          // A2 = A*A
    gemm64_k<1><<<dim3(16,16,3), b, 0, stream>>>(slot(3), slot(0), slot(6), 1,
                                                 slot(0), slot(3), slot(9));          // A3 + Mb
    gemm64_k<2><<<dim3(16,16,3), b, 0, stream>>>(slot(9), slot(6), slot(9), 1,
                                                 slot(0), slot(3), slot(12));         // E = I+A+A2/2+Mb*A3
    tsplit_k<<<dim3(16,16), b, 0, stream>>>(slot(14), slot(15));                      // E2^T
    gemm64_k<0><<<dim3(16,16,1), b, 0, stream>>>(slot(15), slot(13), slot(0), 0,
                                                 slot(0), slot(0), slot(0));          // M1 = E2^T*E1^T
    gemm64_k<0><<<dim3(16,16,1), b, 0, stream>>>(slot(0), slot(12), RT, 0,
                                                 slot(0), slot(0), RT);               // RT = M1*E0^T
    if (ws_ok)
        gemm_big_k<1><<<dim3(1024), b, 0, stream>>>(Xh, RT, out);
    else
        gemm_big_k<2><<<dim3(1024), b, 0, stream>>>(X, RT, out);
}

// Round 5
// 217.478 us; speedup vs baseline: 5.1524x; 1.1156x over previous
//
#include <hip/hip_runtime.h>

#define S 1048576
typedef unsigned short u16;
typedef unsigned int u32;
typedef __attribute__((ext_vector_type(8))) short s8v;   // 8 bf16 (4 VGPRs)
typedef __attribute__((ext_vector_type(4))) float f4v;   // MFMA acc

__device__ __forceinline__ float bf2f(u16 u){
    union { float f; u32 u; } v; v.u = ((u32)u) << 16; return v.f;
}
__device__ __forceinline__ u16 f2bf(float x){
    u32 u = __float_as_uint(x);
    u32 r = (u + 0x7FFFu + ((u >> 16) & 1u)) >> 16;   // RNE
    return (u16)r;
}
__device__ __forceinline__ void splitf(float x, u16& h, u16& l){
    h = f2bf(x);
    l = f2bf(x - bf2f(h));
}
__device__ __forceinline__ float pairf(const u16* H, const u16* L, size_t off){
    return bf2f(H[off]) + bf2f(L[off]);
}
// XOR-swizzled LDS index (u16 units): 128-byte rows of 8 16B chunks, chunk ^= row&7
__device__ __forceinline__ int sidx(int r, int c){ return (r<<6) + (((c) ^ (r&7))<<3); }
// async global->LDS, 16B per lane; LDS dest = wave-uniform base + lane*16
__device__ __forceinline__ void gl16(const void* g, void* l){
    __builtin_amdgcn_global_load_lds((const __attribute__((address_space(1))) void*)g,
                                     (__attribute__((address_space(3))) void*)l, 16, 0, 0);
}

// Fused: blocks [0,768): A_z = 0.5*(G_z - G_z^T) split pair (64x64 tiles, z=bid>>8)
//        blocks [768,...): X fp32 -> bf16 hi only (skipped if grid==768)
__global__ __launch_bounds__(256) void pre_k(const float* __restrict__ G, u16* __restrict__ Abase,
                                             const float* __restrict__ X, u16* __restrict__ Xh){
    __shared__ float Gt[64][65];
    const int bid = blockIdx.x;
    const int t = threadIdx.x;
    if (bid < 768){
        const int bx = bid & 15, by = (bid >> 4) & 15, z = bid >> 8;
        const float* Gz = G + (size_t)z*S;
        u16* Ah = Abase + (size_t)z*2*S;
        u16* Al = Ah + S;
        const int row = t >> 2, cq = (t & 3) << 4;
        const int r0 = by << 6, c0 = bx << 6;
        #pragma unroll
        for (int g = 0; g < 4; ++g){
            float4 v = *(const float4*)(Gz + (size_t)(c0+row)*1024 + r0 + cq + g*4);
            Gt[row][cq+g*4+0]=v.x; Gt[row][cq+g*4+1]=v.y; Gt[row][cq+g*4+2]=v.z; Gt[row][cq+g*4+3]=v.w;
        }
        __syncthreads();
        #pragma unroll
        for (int g = 0; g < 2; ++g){
            const float* p = Gz + (size_t)(r0+row)*1024 + c0 + cq + g*8;
            float4 v0 = *(const float4*)(p);
            float4 v1 = *(const float4*)(p+4);
            float xs[8] = {v0.x,v0.y,v0.z,v0.w,v1.x,v1.y,v1.z,v1.w};
            s8v sh, sl;
            #pragma unroll
            for (int i = 0; i < 8; ++i){
                float gt = Gt[cq + g*8 + i][row];
                u16 h,l; splitf(0.5f*(xs[i]-gt), h, l);
                sh[i] = (short)h; sl[i] = (short)l;
            }
            *(s8v*)(Ah + (size_t)(r0+row)*1024 + c0 + cq + g*8) = sh;
            *(s8v*)(Al + (size_t)(r0+row)*1024 + c0 + cq + g*8) = sl;
        }
    } else {
        const size_t idx8 = ((size_t)(bid-768)*256 + t)*8;
        float4 v0 = *(const float4*)(X+idx8);
        float4 v1 = *(const float4*)(X+idx8+4);
        float xs[8] = {v0.x,v0.y,v0.z,v0.w,v1.x,v1.y,v1.z,v1.w};
        s8v h;
        #pragma unroll
        for (int i = 0; i < 8; ++i) h[i] = (short)f2bf(xs[i]);
        *(s8v*)(Xh+idx8) = h;
    }
}

// acc = A * Bt^T with split-bf16 MFMA (3 passes), DMA staging, double-buffered, 1 barrier/K-step.
// NOTE: no negation anywhere. With skew inputs: A*(A)^T = -A^2 ; (-A^2)*(A)^T = A^3.
// MODE 0: C pair = acc.
// MODE 1: C pair = acc AND O2 = (1/6)I + (1/24)*Bt - (1/120)*Aop + (1/720)*acc
//         (A-op = A2' = -A^2, Bt = A, acc = A^3  =>  O2 = Mb)
// MODE 2: O2 only = I + Pa - 0.5*Pa2 - acc   (A-op = Mb, Bt = A3 => acc = -Mb*A^3; O2 = E)
template<int MODE>
__global__ __launch_bounds__(256) void gemm64_k(const u16* __restrict__ Abase, const u16* __restrict__ Btbase,
                                                u16* __restrict__ Cbase,
                                                const u16* __restrict__ Pab, const u16* __restrict__ Pa2b,
                                                u16* __restrict__ O2base){
    __shared__ u16 lds[2][16384];   // per buf: Ah 0, Al 4096, Bh 8192, Bl 12288 (64x64 u16 each)
    const int z = blockIdx.z;
    const u16* Ah = Abase  + (size_t)z*2*S; const u16* Al = Ah + S;
    const u16* Bh = Btbase + (size_t)z*2*S; const u16* Bl = Bh + S;
    u16* Ch = Cbase + (size_t)z*2*S;        u16* Cl = Ch + S;
    const u16* Pah = Pab + (size_t)z*2*S;   const u16* Pal = Pah + S;
    const u16* P2h = Pa2b + (size_t)z*2*S;  const u16* P2l = P2h + S;
    u16* O2h = O2base + (size_t)z*2*S;      u16* O2l = O2h + S;
    const int t = threadIdx.x;
    const int brow = blockIdx.y << 6, bcol = blockIdx.x << 6;
    const int lane = t & 63, w = t >> 6;
    const int wm = (w >> 1) << 5, wn = (w & 1) << 5;
    const int lr = lane & 15, g = lane >> 4;
    // staging map: per region, wave w issues i=0,1: chunk q=(w*2+i)*64+lane (linear LDS);
    // global source pre-swizzled so LDS linear (r,c) holds global (r, c^(r&7)).
    int qq[2]; size_t goA[2], goB[2];
    #pragma unroll
    for (int i = 0; i < 2; ++i){
        int q = (((w<<1)+i)<<6) + lane;
        int r = q >> 3, c = lane & 7;
        qq[i] = q << 3;
        goA[i] = (size_t)(brow+r)*1024 + ((c^(r&7))<<3);
        goB[i] = (size_t)(bcol+r)*1024 + ((c^(r&7))<<3);
    }
    f4v acc[2][2] = {};
    // prologue
    {
        u16* L = lds[0];
        #pragma unroll
        for (int i = 0; i < 2; ++i){
            gl16(Ah + goA[i], L + qq[i]);
            gl16(Al + goA[i], L + 4096 + qq[i]);
            gl16(Bh + goB[i], L + 8192 + qq[i]);
            gl16(Bl + goB[i], L + 12288 + qq[i]);
        }
    }
    int cur = 0;
    for (int kt = 0; kt < 16; ++kt){
        __syncthreads();   // drains my DMA (vmcnt0) + all waves' -> lds[cur] ready; prev reads done
        if (kt < 15){
            u16* L = lds[cur^1];
            const int k0 = (kt+1) << 6;
            #pragma unroll
            for (int i = 0; i < 2; ++i){
                gl16(Ah + goA[i] + k0, L + qq[i]);
                gl16(Al + goA[i] + k0, L + 4096 + qq[i]);
                gl16(Bh + goB[i] + k0, L + 8192 + qq[i]);
                gl16(Bl + goB[i] + k0, L + 12288 + qq[i]);
            }
        }
        const u16* L = lds[cur];
        #pragma unroll
        for (int ks = 0; ks < 2; ++ks){
            const int ch = (ks << 2) + g;
            s8v a_h[2], a_l[2], b_h[2], b_l[2];
            #pragma unroll
            for (int f = 0; f < 2; ++f){
                const int ra = wm+(f<<4)+lr, rb = wn+(f<<4)+lr;
                a_h[f] = *(const s8v*)&L[sidx(ra,ch)];
                a_l[f] = *(const s8v*)&L[4096 + sidx(ra,ch)];
                b_h[f] = *(const s8v*)&L[8192 + sidx(rb,ch)];
                b_l[f] = *(const s8v*)&L[12288 + sidx(rb,ch)];
            }
            __builtin_amdgcn_s_setprio(1);
            #pragma unroll
            for (int mf = 0; mf < 2; ++mf)
                #pragma unroll
                for (int nf = 0; nf < 2; ++nf){
                    acc[mf][nf] = __builtin_amdgcn_mfma_f32_16x16x32_bf16(a_h[mf], b_h[nf], acc[mf][nf], 0,0,0);
                    acc[mf][nf] = __builtin_amdgcn_mfma_f32_16x16x32_bf16(a_l[mf], b_h[nf], acc[mf][nf], 0,0,0);
                    acc[mf][nf] = __builtin_amdgcn_mfma_f32_16x16x32_bf16(a_h[mf], b_l[nf], acc[mf][nf], 0,0,0);
                }
            __builtin_amdgcn_s_setprio(0);
        }
        cur ^= 1;
    }
    const int orr = g << 2;
    #pragma unroll
    for (int mf = 0; mf < 2; ++mf)
        #pragma unroll
        for (int nf = 0; nf < 2; ++nf)
            #pragma unroll
            for (int r = 0; r < 4; ++r){
                const int orow = brow + wm + (mf<<4) + orr + r;
                const int ocol = bcol + wn + (nf<<4) + lr;
                const size_t off = (size_t)orow*1024 + ocol;
                const float av = acc[mf][nf][r];
                if (MODE == 0 || MODE == 1){
                    u16 h,l; splitf(av, h, l);
                    Ch[off] = h; Cl[off] = l;
                }
                if (MODE == 1){
                    float a  = pairf(Bh, Bl, off);      // A
                    float a2 = pairf(Ah, Al, off);      // A2' = -A^2
                    float mb = (1.0f/24.0f)*a - (1.0f/120.0f)*a2 + (1.0f/720.0f)*av
                             + (orow == ocol ? (1.0f/6.0f) : 0.0f);
                    u16 h,l; splitf(mb, h, l);
                    O2h[off] = h; O2l[off] = l;
                }
                if (MODE == 2){
                    float a  = pairf(Pah, Pal, off);    // A
                    float a2 = pairf(P2h, P2l, off);    // A2' = -A^2
                    float e = a - 0.5f*a2 - av + (orow == ocol ? 1.0f : 0.0f);
                    u16 h,l; splitf(e, h, l);
                    O2h[off] = h; O2l[off] = l;
                }
            }
}

// Out pair = transpose of input pair (bf16), 64x64 LDS tiles.
__global__ __launch_bounds__(256) void tsplit_k(const u16* __restrict__ Eh, u16* __restrict__ Oth){
    __shared__ u16 Th[64][72], Tl[64][72];
    const u16* El = Eh + S; u16* Otl = Oth + S;
    const int t = threadIdx.x;
    const int row = t >> 2, cq = (t & 3) << 4;
    const int r0 = blockIdx.y << 6, c0 = blockIdx.x << 6;
    const size_t ro = (size_t)(r0+row)*1024 + c0 + cq;
    *(s8v*)&Th[row][cq]   = *(const s8v*)(Eh + ro);
    *(s8v*)&Th[row][cq+8] = *(const s8v*)(Eh + ro + 8);
    *(s8v*)&Tl[row][cq]   = *(const s8v*)(El + ro);
    *(s8v*)&Tl[row][cq+8] = *(const s8v*)(El + ro + 8);
    __syncthreads();
    s8v a,b,c,d;
    #pragma unroll
    for (int i = 0; i < 8; ++i){
        a[i] = (short)Th[cq+i][row];   b[i] = (short)Th[cq+8+i][row];
        c[i] = (short)Tl[cq+i][row];   d[i] = (short)Tl[cq+8+i][row];
    }
    const size_t wo = (size_t)(c0+row)*1024 + r0 + cq;
    *(s8v*)(Oth + wo)     = a;
    *(s8v*)(Oth + wo + 8) = b;
    *(s8v*)(Otl + wo)     = c;
    *(s8v*)(Otl + wo + 8) = d;
}

// Y[16384,1024] = X * R.  256x128x64 tile, 8 waves, DMA staging, dbuf, 1 barrier/K-step.
__global__ __launch_bounds__(512) void gemm_big2(const u16* __restrict__ Xh, const u16* __restrict__ Rth,
                                                 float* __restrict__ Y){
    __shared__ u16 lds[2][32768];  // per buf: X 0..16383 (256x64), Bh 16384.. (128x64), Bl 24576..
    const u16* Rtl = Rth + S;
    const int bid = blockIdx.x;
    const int swz = (bid & 7)*64 + (bid >> 3);     // chunked XCD swizzle (512 blocks, bijective)
    const int by = swz >> 3, bx = swz & 7;
    const int brow = by << 8, bcol = bx << 7;
    const int t = threadIdx.x;
    const int lane = t & 63, w = t >> 6;
    const int wm = (w >> 2) << 7, wn = (w & 3) << 5;   // wave tile 128x32
    const int lr = lane & 15, g = lane >> 4;
    int xq[4]; size_t gx[4];
    #pragma unroll
    for (int i = 0; i < 4; ++i){
        int q = (((w<<2)+i)<<6) + lane;
        int r = q >> 3, c = lane & 7;
        xq[i] = q << 3;
        gx[i] = (size_t)(brow+r)*1024 + ((c^(r&7))<<3);
    }
    int bq[2]; size_t gb[2];
    #pragma unroll
    for (int i = 0; i < 2; ++i){
        int q = (((w<<1)+i)<<6) + lane;
        int r = q >> 3, c = lane & 7;
        bq[i] = q << 3;
        gb[i] = (size_t)(bcol+r)*1024 + ((c^(r&7))<<3);
    }
    f4v acc[8][2] = {};
    {
        u16* L = lds[0];
        #pragma unroll
        for (int i = 0; i < 4; ++i) gl16(Xh + gx[i], L + xq[i]);
        #pragma unroll
        for (int i = 0; i < 2; ++i){
            gl16(Rth + gb[i], L + 16384 + bq[i]);
            gl16(Rtl + gb[i], L + 24576 + bq[i]);
        }
    }
    int cur = 0;
    for (int kt = 0; kt < 16; ++kt){
        __syncthreads();
        if (kt < 15){
            u16* L = lds[cur^1];
            const int k0 = (kt+1) << 6;
            #pragma unroll
            for (int i = 0; i < 4; ++i) gl16(Xh + gx[i] + k0, L + xq[i]);
            #pragma unroll
            for (int i = 0; i < 2; ++i){
                gl16(Rth + gb[i] + k0, L + 16384 + bq[i]);
                gl16(Rtl + gb[i] + k0, L + 24576 + bq[i]);
            }
        }
        const u16* L = lds[cur];
        #pragma unroll
        for (int ks = 0; ks < 2; ++ks){
            const int ch = (ks << 2) + g;
            s8v bh[2], bl[2];
            #pragma unroll
            for (int nf = 0; nf < 2; ++nf){
                const int rb = wn+(nf<<4)+lr;
                bh[nf] = *(const s8v*)&L[16384 + sidx(rb,ch)];
                bl[nf] = *(const s8v*)&L[24576 + sidx(rb,ch)];
            }
            __builtin_amdgcn_s_setprio(1);
            #pragma unroll
            for (int mf = 0; mf < 8; ++mf){
                const int ra = wm+(mf<<4)+lr;
                s8v a = *(const s8v*)&L[sidx(ra,ch)];
                #pragma unroll
                for (int nf = 0; nf < 2; ++nf){
                    acc[mf][nf] = __builtin_amdgcn_mfma_f32_16x16x32_bf16(a, bh[nf], acc[mf][nf], 0,0,0);
                    acc[mf][nf] = __builtin_amdgcn_mfma_f32_16x16x32_bf16(a, bl[nf], acc[mf][nf], 0,0,0);
                }
            }
            __builtin_amdgcn_s_setprio(0);
        }
        cur ^= 1;
    }
    const int orr = g << 2;
    #pragma unroll
    for (int mf = 0; mf < 8; ++mf)
        #pragma unroll
        for (int nf = 0; nf < 2; ++nf)
            #pragma unroll
            for (int r = 0; r < 4; ++r){
                int orow = brow + wm + (mf<<4) + orr + r;
                int ocol = bcol + wn + (nf<<4) + lr;
                Y[(size_t)orow*1024 + ocol] = acc[mf][nf][r];
            }
}

// Fallback (no workspace): reg-staged 128x128, X converted on the fly.
__global__ __launch_bounds__(256) void gemm_big_f(const float* __restrict__ Xv, const u16* __restrict__ Rth,
                                                  float* __restrict__ Y){
    __shared__ u16 Xs[128*64], Bhs[128*64], Bls[128*64];
    const u16* Rtl = Rth + S;
    const int bid = blockIdx.x;
    const int swz = (bid & 7)*128 + (bid >> 3);
    const int bx = swz & 7, by = swz >> 3;
    const int brow = by << 7, bcol = bx << 7;
    const int t = threadIdx.x;
    const int sr = t >> 1, cb = (t & 1) << 2;
    const int lane = t & 63, w = t >> 6;
    const int wm = (w >> 1) << 6, wn = (w & 1) << 6;
    const int lr = lane & 15, g = lane >> 4;
    s8v xr[4], bhr[4], blr[4];
    auto load_tile = [&](int k0){
        #pragma unroll
        for (int i = 0; i < 4; ++i){
            const size_t bo = (size_t)(bcol+sr)*1024 + k0 + ((cb+i)<<3);
            bhr[i] = *(const s8v*)(Rth + bo);
            blr[i] = *(const s8v*)(Rtl + bo);
        }
        #pragma unroll
        for (int i = 0; i < 4; ++i){
            const float* p = Xv + (size_t)(brow+sr)*1024 + k0 + ((cb+i)<<3);
            float4 f0 = *(const float4*)(p), f1 = *(const float4*)(p+4);
            float xs[8] = {f0.x,f0.y,f0.z,f0.w,f1.x,f1.y,f1.z,f1.w};
            #pragma unroll
            for (int j = 0; j < 8; ++j) xr[i][j] = (short)f2bf(xs[j]);
        }
    };
    load_tile(0);
    f4v acc[4][4] = {};
    for (int k0 = 0; k0 < 1024; k0 += 64){
        __syncthreads();
        #pragma unroll
        for (int i = 0; i < 4; ++i){
            const int si = sidx(sr, cb+i);
            *(s8v*)&Xs[si]  = xr[i];
            *(s8v*)&Bhs[si] = bhr[i];
            *(s8v*)&Bls[si] = blr[i];
        }
        __syncthreads();
        if (k0 < 960) load_tile(k0 + 64);
        #pragma unroll
        for (int ks = 0; ks < 2; ++ks){
            const int ch = (ks << 2) + g;
            s8v bhf[4], blf[4];
            #pragma unroll
            for (int nf = 0; nf < 4; ++nf){
                bhf[nf] = *(const s8v*)&Bhs[sidx(wn+(nf<<4)+lr, ch)];
                blf[nf] = *(const s8v*)&Bls[sidx(wn+(nf<<4)+lr, ch)];
            }
            #pragma unroll
            for (int mf = 0; mf < 4; ++mf){
                s8v ah = *(const s8v*)&Xs[sidx(wm+(mf<<4)+lr, ch)];
                #pragma unroll
                for (int nf = 0; nf < 4; ++nf){
                    acc[mf][nf] = __builtin_amdgcn_mfma_f32_16x16x32_bf16(ah, bhf[nf], acc[mf][nf], 0,0,0);
                    acc[mf][nf] = __builtin_amdgcn_mfma_f32_16x16x32_bf16(ah, blf[nf], acc[mf][nf], 0,0,0);
                }
            }
        }
    }
    const int orr = g << 2;
    #pragma unroll
    for (int mf = 0; mf < 4; ++mf)
        #pragma unroll
        for (int nf = 0; nf < 4; ++nf)
            #pragma unroll
            for (int r = 0; r < 4; ++r){
                int orow = brow + wm + (mf<<4) + orr + r;
                int ocol = bcol + wn + (nf<<4) + lr;
                Y[(size_t)orow*1024 + ocol] = acc[mf][nf][r];
            }
}

extern "C" void kernel_launch(void* const* d_in, const int* in_sizes, int n_in,
                              void* d_out, int out_size, void* d_ws, size_t ws_size,
                              hipStream_t stream) {
    const float* X = (const float*)d_in[0];   // [16384,1024] fp32
    const float* G = (const float*)d_in[1];   // [3,1024,1024] fp32
    float* out = (float*)d_out;
    u16* ob = (u16*)d_out;                    // 16 pair-slots of 2*S u16 each
    auto slot = [&](int i){ return ob + (size_t)i*2*S; };
    u16* RT = (u16*)d_ws;                     // R^T split pair (4 MB)
    u16* Xh = RT + (size_t)2*S;               // X hi bf16 (32 MB)
    const bool ws_ok = ws_size >= (size_t)36*S; // bytes: 2S*2 (RT) + 16S*2 (Xh)

    dim3 b(256);
    // slots: A:0-2  A2':3-5  A3:6-8  Mb:9-11  E:12-14  E2t:15  M1:0
    pre_k<<<dim3(ws_ok ? 8960 : 768), b, 0, stream>>>(G, slot(0), X, Xh);
    gemm64_k<0><<<dim3(16,16,3), b, 0, stream>>>(slot(0), slot(0), slot(3),
                                                 slot(0), slot(0), slot(3));          // A2' = A*A^T = -A^2
    gemm64_k<1><<<dim3(16,16,3), b, 0, stream>>>(slot(3), slot(0), slot(6),
                                                 slot(0), slot(3), slot(9));          // A3 = A2'*A^T ; Mb
    gemm64_k<2><<<dim3(16,16,3), b, 0, stream>>>(slot(9), slot(6), slot(9),
                                                 slot(0), slot(3), slot(12));         // E = I+A+A^2/2-acc
    tsplit_k<<<dim3(16,16), b, 0, stream>>>(slot(14), slot(15));                      // E2^T
    gemm64_k<0><<<dim3(16,16,1), b, 0, stream>>>(slot(15), slot(13), slot(0),
                                                 slot(0), slot(0), slot(0));          // M1 = E2^T*E1^T
    gemm64_k<0><<<dim3(16,16,1), b, 0, stream>>>(slot(0), slot(12), RT,
                                                 slot(0), slot(0), RT);               // RT = M1*E0^T
    if (ws_ok)
        gemm_big2<<<dim3(512), dim3(512), 0, stream>>>(Xh, RT, out);
    else
        gemm_big_f<<<dim3(1024), b, 0, stream>>>(X, RT, out);
}